// Round 2
// baseline (165.450 us; speedup 1.0000x reference)
//
#include <hip/hip_runtime.h>
#include <math.h>

// loss = -sum_ij d1[i,j] * log(d2[i,j] + 1e-5), fp32 in, scalar fp32 out.
// Memory-bound: 134 MB read @ ~6.3 TB/s -> ~21 us floor.
// R1 lesson: rolled loop had only 2 loads in flight/wave -> latency-bound
// at 2.4 TB/s. Fix: batch-prefetch 4 float4 pairs (8 dwordx4 in flight),
// 4 accumulator ladders, VGPR<=64 for full occupancy.

#define EPS 1e-5f
#define IT 4  // float4 pairs prefetched per thread per outer iteration

__global__ void cep_zero_kernel(float* out) {
    out[0] = 0.0f;
}

__global__ __launch_bounds__(256) void cep_loss_kernel(
        const float4* __restrict__ d1,
        const float4* __restrict__ d2,
        float* __restrict__ out,
        int n4) {
    int tid = blockIdx.x * blockDim.x + threadIdx.x;
    int stride = gridDim.x * blockDim.x;

    float acc0 = 0.0f, acc1 = 0.0f, acc2 = 0.0f, acc3 = 0.0f;

    // grid is sized so this outer loop executes exactly once for N=4096^2;
    // kept as a loop for shape-robustness.
    for (int i = tid; i < n4; i += stride * IT) {
        float4 a[IT], b[IT];
        #pragma unroll
        for (int j = 0; j < IT; j++) {
            int idx = i + j * stride;
            a[j] = d1[idx];
            b[j] = d2[idx];
        }
        #pragma unroll
        for (int j = 0; j < IT; j++) {
            acc0 += a[j].x * __logf(b[j].x + EPS);
            acc1 += a[j].y * __logf(b[j].y + EPS);
            acc2 += a[j].z * __logf(b[j].z + EPS);
            acc3 += a[j].w * __logf(b[j].w + EPS);
        }
    }

    float acc = (acc0 + acc1) + (acc2 + acc3);

    // wave-64 shuffle reduction
    #pragma unroll
    for (int off = 32; off > 0; off >>= 1)
        acc += __shfl_down(acc, off, 64);

    __shared__ float wave_sums[4];  // 256 threads / 64 lanes
    int lane = threadIdx.x & 63;
    int wid  = threadIdx.x >> 6;
    if (lane == 0) wave_sums[wid] = acc;
    __syncthreads();

    if (threadIdx.x == 0) {
        float s = wave_sums[0] + wave_sums[1] + wave_sums[2] + wave_sums[3];
        atomicAdd(out, -s);  // device-scope by default on CDNA
    }
}

extern "C" void kernel_launch(void* const* d_in, const int* in_sizes, int n_in,
                              void* d_out, int out_size, void* d_ws, size_t ws_size,
                              hipStream_t stream) {
    const float4* d1 = (const float4*)d_in[0];
    const float4* d2 = (const float4*)d_in[1];
    float* out = (float*)d_out;

    int n = in_sizes[0];        // 4096*4096 = 16,777,216
    int n4 = n / 4;             // 4,194,304 float4 elements

    cep_zero_kernel<<<1, 1, 0, stream>>>(out);

    const int block = 256;
    // grid * block * IT == n4 exactly -> outer loop runs once
    const int grid = (n4 + block * IT - 1) / (block * IT);  // 4096
    cep_loss_kernel<<<grid, block, 0, stream>>>(d1, d2, out, n4);
}

// Round 3
// 144.589 us; speedup vs baseline: 1.1443x; 1.1443x over previous
//
#include <hip/hip_runtime.h>
#include <math.h>

// loss = -sum_ij d1[i,j] * log(d2[i,j] + 1e-5), fp32 in, scalar fp32 out.
// Roofline: 134 MB read -> ~21 us @ 6.3 TB/s.
// R1/R2 lesson: VALUBusy ~11%, ~2.2 TB/s -> latency-bound. Compiler minimized
// VGPRs (12/28) so no cross-iteration load-ahead existed; waves serialize
// load -> full-latency stall -> 60cy compute. Fix: explicit 2-deep software
// pipeline with rotating register buffers (4 loads = 4KB/wave in flight
// during compute), VGPR<=64 to keep 8 waves/SIMD.

#define EPS 1e-5f
#define BLOCK 256
#define PAIRS 2   // float4 pairs per pipeline stage
#define STAGES 4  // stages per thread -> 8 float4 pairs/thread total

__global__ __launch_bounds__(BLOCK) void cep_loss_kernel(
        const float4* __restrict__ d1,
        const float4* __restrict__ d2,
        float* __restrict__ partials,
        int n4) {
    int tid = blockIdx.x * blockDim.x + threadIdx.x;
    int stride = gridDim.x * blockDim.x;

    float acc0 = 0.0f, acc1 = 0.0f, acc2 = 0.0f, acc3 = 0.0f;

    float4 a0[PAIRS], b0[PAIRS], a1[PAIRS], b1[PAIRS];

    int base = tid;
    #pragma unroll
    for (int p = 0; p < PAIRS; p++) {
        a0[p] = d1[base + p * stride];
        b0[p] = d2[base + p * stride];
    }

    #pragma unroll
    for (int s = 1; s < STAGES; s++) {
        int nb = base + PAIRS * stride;
        // prefetch next stage (4 dwordx4 in flight during compute below)
        #pragma unroll
        for (int p = 0; p < PAIRS; p++) {
            a1[p] = d1[nb + p * stride];
            b1[p] = d2[nb + p * stride];
        }
        // compute current stage
        #pragma unroll
        for (int p = 0; p < PAIRS; p++) {
            acc0 += a0[p].x * __logf(b0[p].x + EPS);
            acc1 += a0[p].y * __logf(b0[p].y + EPS);
            acc2 += a0[p].z * __logf(b0[p].z + EPS);
            acc3 += a0[p].w * __logf(b0[p].w + EPS);
        }
        // rotate
        #pragma unroll
        for (int p = 0; p < PAIRS; p++) { a0[p] = a1[p]; b0[p] = b1[p]; }
        base = nb;
    }

    // epilogue stage
    #pragma unroll
    for (int p = 0; p < PAIRS; p++) {
        acc0 += a0[p].x * __logf(b0[p].x + EPS);
        acc1 += a0[p].y * __logf(b0[p].y + EPS);
        acc2 += a0[p].z * __logf(b0[p].z + EPS);
        acc3 += a0[p].w * __logf(b0[p].w + EPS);
    }

    float acc = (acc0 + acc1) + (acc2 + acc3);

    // wave-64 shuffle reduction
    #pragma unroll
    for (int off = 32; off > 0; off >>= 1)
        acc += __shfl_down(acc, off, 64);

    __shared__ float wave_sums[BLOCK / 64];
    int lane = threadIdx.x & 63;
    int wid  = threadIdx.x >> 6;
    if (lane == 0) wave_sums[wid] = acc;
    __syncthreads();

    if (threadIdx.x == 0) {
        float s = wave_sums[0] + wave_sums[1] + wave_sums[2] + wave_sums[3];
        partials[blockIdx.x] = s;  // deterministic: no atomics, no zero-init needed
    }
}

__global__ __launch_bounds__(BLOCK) void cep_final_kernel(
        const float* __restrict__ partials, float* __restrict__ out, int nparts) {
    float acc = 0.0f;
    for (int i = threadIdx.x; i < nparts; i += BLOCK)
        acc += partials[i];

    #pragma unroll
    for (int off = 32; off > 0; off >>= 1)
        acc += __shfl_down(acc, off, 64);

    __shared__ float wave_sums[BLOCK / 64];
    int lane = threadIdx.x & 63;
    int wid  = threadIdx.x >> 6;
    if (lane == 0) wave_sums[wid] = acc;
    __syncthreads();

    if (threadIdx.x == 0) {
        float s = wave_sums[0] + wave_sums[1] + wave_sums[2] + wave_sums[3];
        out[0] = -s;
    }
}

extern "C" void kernel_launch(void* const* d_in, const int* in_sizes, int n_in,
                              void* d_out, int out_size, void* d_ws, size_t ws_size,
                              hipStream_t stream) {
    const float4* d1 = (const float4*)d_in[0];
    const float4* d2 = (const float4*)d_in[1];
    float* out = (float*)d_out;
    float* partials = (float*)d_ws;

    int n = in_sizes[0];        // 4096*4096 = 16,777,216
    int n4 = n / 4;             // 4,194,304 float4 elements

    // grid * BLOCK * STAGES * PAIRS == n4 exactly (N fixed at 4096^2)
    const int per_thread = STAGES * PAIRS;                       // 8 float4 pairs
    const int grid = n4 / (BLOCK * per_thread);                  // 2048

    cep_loss_kernel<<<grid, BLOCK, 0, stream>>>(d1, d2, partials, n4);
    cep_final_kernel<<<1, BLOCK, 0, stream>>>(partials, out, grid);
}